// Round 1
// baseline (694.036 us; speedup 1.0000x reference)
//
#include <hip/hip_runtime.h>
#include <cstddef>

#define B_ 4
#define S_ 2048
#define H_ 8
#define D_ 64
#define E_ 512

// ---------------- weight prep ----------------
// G[d][c] = sum_e Wq[e][d] * Wk[e][c]   (64x64)
__global__ __launch_bounds__(256) void prep_G(const float* __restrict__ Wq,
                                              const float* __restrict__ Wk,
                                              float* __restrict__ G) {
    int idx = blockIdx.x * 256 + threadIdx.x;   // 4096 total
    int d = idx >> 6, c = idx & 63;
    float acc = 0.f;
#pragma unroll 8
    for (int e = 0; e < 64; ++e) acc += Wq[e * 64 + d] * Wk[e * 64 + c];
    G[idx] = acc;
}

// W2[e][h*64+c] = sum_d Wo[e][h*64+d] * Wv[d][c]   (512x512)
__global__ __launch_bounds__(256) void prep_W2(const float* __restrict__ Wo,
                                               const float* __restrict__ Wv,
                                               float* __restrict__ W2) {
    int idx = blockIdx.x * 256 + threadIdx.x;   // 262144 total
    int e = idx >> 9, f = idx & 511;
    int h = f >> 6, c = f & 63;
    const float* wo = Wo + e * 512 + h * 64;
    float acc = 0.f;
#pragma unroll 8
    for (int d = 0; d < 64; ++d) acc += wo[d] * Wv[d * 64 + c];
    W2[idx] = acc;
}

// ---------------- flash attention (fp32) ----------------
// dst[d][j] = src_base[j*E_ + d]  (64 rows of a head-slice, transposed into LDS)
__device__ __forceinline__ void stage_tile(float (*dst)[68], const float* __restrict__ src_base,
                                           int tid) {
    int j = tid >> 2, part = tid & 3;
    const float* row = src_base + (size_t)j * E_;
#pragma unroll
    for (int q = 0; q < 4; ++q) {
        int d0 = part * 4 + q * 16;
        float4 v = *(const float4*)(row + d0);
        dst[d0 + 0][j] = v.x;
        dst[d0 + 1][j] = v.y;
        dst[d0 + 2][j] = v.z;
        dst[d0 + 3][j] = v.w;
    }
}

// grid: B*H*(S/64) = 1024 blocks, 256 threads.
// Per block: 64 Q-rows of one (b,h). U-tile computed in-kernel: U = Xq @ G.
// Online softmax over K-chunks of 64 (K/V rows come from the queries tensor, per reference).
__global__ __launch_bounds__(256) void attn_kernel(const float* __restrict__ X,
                                                   const float* __restrict__ G,
                                                   float* __restrict__ AO) {
    __shared__ float UT[64][68];   // UT[d][i] = U[i][d]
    __shared__ float XT[64][68];   // XT[d][j] = Xk[j][d]
    __shared__ float Pp[64][68];   // Pp[i][j] = softmax numerator

    const int tid = threadIdx.x;
    const int qt = blockIdx.x & 31;
    const int h  = (blockIdx.x >> 5) & 7;
    const int b  = blockIdx.x >> 8;
    const int s0 = qt * 64;
    const int ti = tid >> 4, tj = tid & 15;

    // Stage Q-tile raw rows into XT, then UT = (Xq @ G)^T.
    stage_tile(XT, X + ((size_t)(b * S_ + s0) * E_) + h * 64, tid);
    __syncthreads();
    {
        float ua[4][4] = {{0.f}};
        for (int dd = 0; dd < 64; ++dd) {
            float4 xf = *(const float4*)&XT[dd][ti * 4];
            float xr[4] = {xf.x, xf.y, xf.z, xf.w};
            float gg[4];
#pragma unroll
            for (int k = 0; k < 4; ++k) gg[k] = G[dd * 64 + tj + 16 * k];
#pragma unroll
            for (int r = 0; r < 4; ++r)
#pragma unroll
                for (int k = 0; k < 4; ++k) ua[r][k] += xr[r] * gg[k];
        }
#pragma unroll
        for (int r = 0; r < 4; ++r)
#pragma unroll
            for (int k = 0; k < 4; ++k) UT[tj + 16 * k][ti * 4 + r] = ua[r][k];
        // UT-write -> UT-read is protected by the barrier pair at the top of the chunk loop.
    }

    float m[4], l[4], AOacc[4][4];
#pragma unroll
    for (int r = 0; r < 4; ++r) {
        m[r] = -1e30f;
        l[r] = 0.f;
#pragma unroll
        for (int k = 0; k < 4; ++k) AOacc[r][k] = 0.f;
    }
    const float kScale = 1.4426950408889634f / 8.0f;   // log2(e) * (1/sqrt(64))

    for (int sk = 0; sk < S_; sk += 64) {
        __syncthreads();   // previous chunk's XT readers done
        stage_tile(XT, X + ((size_t)(b * S_ + sk) * E_) + h * 64, tid);
        __syncthreads();

        // scores: Sc[r][q] = U[i_r] . Xk[j_q]
        float Sc[4][4] = {{0.f}};
        for (int d = 0; d < 64; ++d) {
            float4 uf = *(const float4*)&UT[d][ti * 4];
            float4 xf = *(const float4*)&XT[d][tj * 4];
            float ur[4] = {uf.x, uf.y, uf.z, uf.w};
            float xr[4] = {xf.x, xf.y, xf.z, xf.w};
#pragma unroll
            for (int r = 0; r < 4; ++r)
#pragma unroll
                for (int q = 0; q < 4; ++q) Sc[r][q] += ur[r] * xr[q];
        }

        // online softmax update (rows shared by the 16 tj-lanes of each quarter-wave)
#pragma unroll
        for (int r = 0; r < 4; ++r) {
            float sv0 = Sc[r][0] * kScale, sv1 = Sc[r][1] * kScale;
            float sv2 = Sc[r][2] * kScale, sv3 = Sc[r][3] * kScale;
            float mx = fmaxf(fmaxf(sv0, sv1), fmaxf(sv2, sv3));
#pragma unroll
            for (int off = 8; off > 0; off >>= 1) mx = fmaxf(mx, __shfl_xor(mx, off));
            float nm = fmaxf(m[r], mx);
            float alpha = exp2f(m[r] - nm);
            float p0 = exp2f(sv0 - nm), p1 = exp2f(sv1 - nm);
            float p2 = exp2f(sv2 - nm), p3 = exp2f(sv3 - nm);
            *(float4*)&Pp[ti * 4 + r][tj * 4] = make_float4(p0, p1, p2, p3);
            float rs = p0 + p1 + p2 + p3;
#pragma unroll
            for (int off = 8; off > 0; off >>= 1) rs += __shfl_xor(rs, off);
            l[r] = l[r] * alpha + rs;
            m[r] = nm;
#pragma unroll
            for (int k = 0; k < 4; ++k) AOacc[r][k] *= alpha;
        }
        __syncthreads();   // Pp visible to all readers

        // PV: AO[i][d] += sum_j P[i][j] * Xk[j][d],  d = tj + 16*k
#pragma unroll 2
        for (int j = 0; j < 64; ++j) {
            float pr[4], xv[4];
#pragma unroll
            for (int r = 0; r < 4; ++r) pr[r] = Pp[ti * 4 + r][j];
#pragma unroll
            for (int k = 0; k < 4; ++k) xv[k] = XT[tj + 16 * k][j];
#pragma unroll
            for (int r = 0; r < 4; ++r)
#pragma unroll
                for (int k = 0; k < 4; ++k) AOacc[r][k] += pr[r] * xv[k];
        }
    }

    float inv[4];
#pragma unroll
    for (int r = 0; r < 4; ++r) inv[r] = 1.0f / l[r];
#pragma unroll
    for (int r = 0; r < 4; ++r) {
        float* orow = AO + ((size_t)(b * S_ + s0 + ti * 4 + r) * E_) + h * 64;
#pragma unroll
        for (int k = 0; k < 4; ++k) orow[tj + 16 * k] = AOacc[r][k] * inv[r];
    }
}

// ---------------- output GEMM: out = AO @ W2^T + bo ----------------
// grid: (8192/64) x (512/64) = 1024 blocks
__global__ __launch_bounds__(256) void out_gemm(const float* __restrict__ Aof,
                                                const float* __restrict__ W2,
                                                const float* __restrict__ bo,
                                                float* __restrict__ out) {
    __shared__ float AT[64][68];   // AT[k][i] = Aof[r0+i][k0+k]
    __shared__ float WT[64][68];   // WT[k][e] = W2[e0+e][k0+k]
    const int tid = threadIdx.x;
    const int et = blockIdx.x & 7;
    const int rt = blockIdx.x >> 3;
    const int r0 = rt * 64, e0 = et * 64;
    const int ti = tid >> 4, tj = tid & 15;
    float acc[4][4] = {{0.f}};

    for (int k0 = 0; k0 < 512; k0 += 64) {
        __syncthreads();
        {
            int i = tid >> 2, part = tid & 3;
            const float* arow = Aof + (size_t)(r0 + i) * 512 + k0;
            const float* wrow = W2 + (size_t)(e0 + i) * 512 + k0;
#pragma unroll
            for (int q = 0; q < 4; ++q) {
                int d0 = part * 4 + q * 16;
                float4 va = *(const float4*)(arow + d0);
                AT[d0 + 0][i] = va.x; AT[d0 + 1][i] = va.y;
                AT[d0 + 2][i] = va.z; AT[d0 + 3][i] = va.w;
                float4 vw = *(const float4*)(wrow + d0);
                WT[d0 + 0][i] = vw.x; WT[d0 + 1][i] = vw.y;
                WT[d0 + 2][i] = vw.z; WT[d0 + 3][i] = vw.w;
            }
        }
        __syncthreads();
        for (int k = 0; k < 64; ++k) {
            float4 af = *(const float4*)&AT[k][ti * 4];
            float4 wf = *(const float4*)&WT[k][tj * 4];
            float ar[4] = {af.x, af.y, af.z, af.w};
            float wr[4] = {wf.x, wf.y, wf.z, wf.w};
#pragma unroll
            for (int r = 0; r < 4; ++r)
#pragma unroll
                for (int q = 0; q < 4; ++q) acc[r][q] += ar[r] * wr[q];
        }
    }
    float4 bv = *(const float4*)(bo + e0 + tj * 4);
#pragma unroll
    for (int r = 0; r < 4; ++r) {
        float4 o = make_float4(acc[r][0] + bv.x, acc[r][1] + bv.y,
                               acc[r][2] + bv.z, acc[r][3] + bv.w);
        *(float4*)(out + (size_t)(r0 + ti * 4 + r) * 512 + e0 + tj * 4) = o;
    }
}

extern "C" void kernel_launch(void* const* d_in, const int* in_sizes, int n_in,
                              void* d_out, int out_size, void* d_ws, size_t ws_size,
                              hipStream_t stream) {
    (void)in_sizes; (void)n_in; (void)out_size; (void)ws_size;
    const float* X  = (const float*)d_in[0];   // queries (K and V also derive from this, per reference)
    const float* Wq = (const float*)d_in[3];
    const float* Wk = (const float*)d_in[4];
    const float* Wv = (const float*)d_in[5];
    const float* Wo = (const float*)d_in[6];
    const float* bo = (const float*)d_in[7];

    float* ws = (float*)d_ws;
    float* G  = ws;                 // 64*64           = 4096 floats
    float* W2 = ws + 4096;          // 512*512         = 262144 floats
    float* AO = W2 + 262144;        // B*S*E           = 4194304 floats  (~17.8 MB total)

    prep_G<<<16, 256, 0, stream>>>(Wq, Wk, G);
    prep_W2<<<1024, 256, 0, stream>>>(Wo, Wv, W2);
    attn_kernel<<<1024, 256, 0, stream>>>(X, G, AO);
    out_gemm<<<1024, 256, 0, stream>>>(AO, W2, bo, (float*)d_out);
}

// Round 2
// 214.968 us; speedup vs baseline: 3.2286x; 3.2286x over previous
//
#include <hip/hip_runtime.h>
#include <cstddef>

#define S_ 2048
#define E_ 512

typedef __attribute__((ext_vector_type(8))) short bf16x8;
typedef __attribute__((ext_vector_type(4))) float f32x4;

__device__ __forceinline__ unsigned short f2bf(float f) {
    union { float f; unsigned u; } v; v.f = f;
    return (unsigned short)((v.u + 0x7FFFu + ((v.u >> 16) & 1u)) >> 16);
}

// ---------------- weight prep ----------------
// GT[c][d] = kScale * sum_e Wq[e][d]*Wk[e][c]   (bf16, 64x64; kScale = log2(e)/sqrt(64))
__global__ __launch_bounds__(256) void prep_GT(const float* __restrict__ Wq,
                                               const float* __restrict__ Wk,
                                               unsigned short* __restrict__ GT) {
    int idx = blockIdx.x * 256 + threadIdx.x;   // 4096
    int c = idx >> 6, d = idx & 63;
    float acc = 0.f;
#pragma unroll 8
    for (int e = 0; e < 64; ++e) acc += Wq[e * 64 + d] * Wk[e * 64 + c];
    GT[c * 64 + d] = f2bf(acc * 0.18033688011112042f);
}

// W2[e][h*64+c] = sum_d Wo[e][h*64+d] * Wv[d][c]   (bf16, 512x512)
__global__ __launch_bounds__(256) void prep_W2bf(const float* __restrict__ Wo,
                                                 const float* __restrict__ Wv,
                                                 unsigned short* __restrict__ W2) {
    int idx = blockIdx.x * 256 + threadIdx.x;   // 262144
    int e = idx >> 9, f = idx & 511;
    int h = f >> 6, c = f & 63;
    const float* wo = Wo + e * 512 + h * 64;
    float acc = 0.f;
#pragma unroll 8
    for (int d = 0; d < 64; ++d) acc += wo[d] * Wv[d * 64 + c];
    W2[idx] = acc >= 0.f || acc < 0.f ? f2bf(acc) : 0;   // (finite inputs; plain cvt)
}

// Xbf[b][s][e] = bf16(X);  XTg[b][h][d][s] = bf16(X[b][s][h*64+d])
__global__ __launch_bounds__(256) void prep_X(const float* __restrict__ X,
                                              unsigned short* __restrict__ Xbf,
                                              unsigned short* __restrict__ XTg) {
    __shared__ unsigned short T[64][72];
    const int tid = threadIdx.x;
    const int st = blockIdx.x & 31, h = (blockIdx.x >> 5) & 7, b = blockIdx.x >> 8;
    const int s0 = st * 64;
    const int j = tid >> 2, g = tid & 3;
    const float* src = X + ((size_t)(b * S_ + s0 + j) * E_) + h * 64 + g * 16;
    unsigned short us[16];
#pragma unroll
    for (int i = 0; i < 16; i += 4) {
        float4 f = *(const float4*)(src + i);
        us[i] = f2bf(f.x); us[i + 1] = f2bf(f.y);
        us[i + 2] = f2bf(f.z); us[i + 3] = f2bf(f.w);
    }
    size_t xb = ((size_t)(b * S_ + s0 + j) * E_) + h * 64 + g * 16;
    *(uint4*)&Xbf[xb]     = *(uint4*)&us[0];
    *(uint4*)&Xbf[xb + 8] = *(uint4*)&us[8];
#pragma unroll
    for (int i = 0; i < 16; ++i) T[g * 16 + i][j] = us[i];
    __syncthreads();
    const int d = tid >> 2;
    size_t tb = ((size_t)((b * 8 + h) * 64 + d)) * S_ + s0 + g * 16;
    *(uint4*)&XTg[tb]     = *(uint4*)&T[d][g * 16];
    *(uint4*)&XTg[tb + 8] = *(uint4*)&T[d][g * 16 + 8];
}

// ---------------- MFMA flash attention ----------------
// 1024 blocks (b,h,qtile of 64), 256 thr = 4 waves; wave w owns q-slab [16w,16w+16).
// Sc^T orientation: QK MFMA computes D[m=key][n=query] so softmax reduces in-register.
__global__ __launch_bounds__(256, 4) void attn_mfma(const unsigned short* __restrict__ Xbf,
                                                    const unsigned short* __restrict__ XTg,
                                                    const unsigned short* __restrict__ GT,
                                                    unsigned short* __restrict__ AObf) {
    __shared__ unsigned short Ubf[64][72];   // U[q][e]  (wave-private rows)
    __shared__ unsigned short Xrm[64][72];   // X[j][d]  key-chunk row-major
    __shared__ unsigned short XT [64][72];   // X^T[d][j] key-chunk transposed
    __shared__ unsigned short Pbf[64][72];   // P[q][k]  (wave-private rows)

    const int tid = threadIdx.x;
    const int w = tid >> 6, lane = tid & 63;
    const int quad = lane >> 4, qidx = lane & 15;
    const int qt = blockIdx.x & 31, h = (blockIdx.x >> 5) & 7, b = blockIdx.x >> 8;
    const int s0 = qt * 64;
    const int jj = tid >> 2, g = tid & 3;

    // stage Q-tile rows into Xrm
    {
        const unsigned short* src = Xbf + ((size_t)(b * S_ + s0 + jj)) * E_ + h * 64 + g * 16;
        *(uint4*)&Xrm[jj][g * 16]     = *(const uint4*)(src);
        *(uint4*)&Xrm[jj][g * 16 + 8] = *(const uint4*)(src + 8);
    }
    __syncthreads();

    // U = Xq @ G (scaled), C-layout -> Ubf rows [16w..16w+16)
    {
        f32x4 uacc[4] = {{0,0,0,0},{0,0,0,0},{0,0,0,0},{0,0,0,0}};
#pragma unroll
        for (int ks = 0; ks < 2; ++ks) {
            bf16x8 aX = *(const bf16x8*)&Xrm[16 * w + qidx][ks * 32 + quad * 8];
#pragma unroll
            for (int nt = 0; nt < 4; ++nt) {
                bf16x8 bG = *(const bf16x8*)&GT[(qidx + 16 * nt) * 64 + ks * 32 + quad * 8];
                uacc[nt] = __builtin_amdgcn_mfma_f32_16x16x32_bf16(aX, bG, uacc[nt], 0, 0, 0);
            }
        }
#pragma unroll
        for (int nt = 0; nt < 4; ++nt)
#pragma unroll
            for (int r = 0; r < 4; ++r)
                Ubf[16 * w + quad * 4 + r][qidx + 16 * nt] = f2bf(uacc[nt][r]);
    }

    float ml = -1e30f, ll = 0.f;
    f32x4 AO[4] = {{0,0,0,0},{0,0,0,0},{0,0,0,0},{0,0,0,0}};

    for (int sk = 0; sk < S_; sk += 64) {
        __syncthreads();   // prev chunk readers done (also covers Ubf/Xrm handoff)
        {
            const unsigned short* src = Xbf + ((size_t)(b * S_ + sk + jj)) * E_ + h * 64 + g * 16;
            *(uint4*)&Xrm[jj][g * 16]     = *(const uint4*)(src);
            *(uint4*)&Xrm[jj][g * 16 + 8] = *(const uint4*)(src + 8);
            const unsigned short* srct = XTg + ((size_t)((b * 8 + h) * 64 + jj)) * S_ + sk + g * 16;
            *(uint4*)&XT[jj][g * 16]     = *(const uint4*)(srct);
            *(uint4*)&XT[jj][g * 16 + 8] = *(const uint4*)(srct + 8);
        }
        __syncthreads();

        // Sc^T[k][q]: A = X-chunk rows (m=key), B = U rows (n=query)
        f32x4 sc[4] = {{0,0,0,0},{0,0,0,0},{0,0,0,0},{0,0,0,0}};
#pragma unroll
        for (int ks = 0; ks < 2; ++ks) {
            bf16x8 bU = *(const bf16x8*)&Ubf[16 * w + qidx][ks * 32 + quad * 8];
#pragma unroll
            for (int mt = 0; mt < 4; ++mt) {
                bf16x8 aX = *(const bf16x8*)&Xrm[16 * mt + qidx][ks * 32 + quad * 8];
                sc[mt] = __builtin_amdgcn_mfma_f32_16x16x32_bf16(aX, bU, sc[mt], 0, 0, 0);
            }
        }

        // online softmax: lane holds 16 key-scores for query q = s0+16w+qidx
        float mx = -1e30f;
#pragma unroll
        for (int mt = 0; mt < 4; ++mt)
#pragma unroll
            for (int r = 0; r < 4; ++r) mx = fmaxf(mx, sc[mt][r]);
        mx = fmaxf(mx, __shfl_xor(mx, 16));
        mx = fmaxf(mx, __shfl_xor(mx, 32));
        float nm = fmaxf(ml, mx);
        float alpha = exp2f(ml - nm);
        ml = nm;
        float rs = 0.f;
#pragma unroll
        for (int mt = 0; mt < 4; ++mt) {
            unsigned short pv[4];
#pragma unroll
            for (int r = 0; r < 4; ++r) {
                float p = exp2f(sc[mt][r] - nm);
                rs += p;
                pv[r] = f2bf(p);
            }
            *(ushort4*)&Pbf[16 * w + qidx][16 * mt + 4 * quad] =
                make_ushort4(pv[0], pv[1], pv[2], pv[3]);
        }
        rs += __shfl_xor(rs, 16);
        rs += __shfl_xor(rs, 32);
        ll = ll * alpha + rs;

        // redistribute alpha to AO's C-layout rows (q = 16w + quad*4 + r)
        float a4[4];
#pragma unroll
        for (int r = 0; r < 4; ++r) a4[r] = __shfl(alpha, (lane & 48) | (quad * 4 + r));
#pragma unroll
        for (int nt = 0; nt < 4; ++nt) {
            AO[nt][0] *= a4[0]; AO[nt][1] *= a4[1];
            AO[nt][2] *= a4[2]; AO[nt][3] *= a4[3];
        }

        // PV: A = P rows (m=q), B = XT rows (n=d); Pbf is wave-private (no barrier)
#pragma unroll
        for (int ks = 0; ks < 2; ++ks) {
            bf16x8 aP = *(const bf16x8*)&Pbf[16 * w + qidx][ks * 32 + quad * 8];
#pragma unroll
            for (int nt = 0; nt < 4; ++nt) {
                bf16x8 bX = *(const bf16x8*)&XT[qidx + 16 * nt][ks * 32 + quad * 8];
                AO[nt] = __builtin_amdgcn_mfma_f32_16x16x32_bf16(aP, bX, AO[nt], 0, 0, 0);
            }
        }
    }

    // epilogue: normalize, bounce through LDS for coalesced bf16 store
    float linv = 1.0f / ll;
    float l4[4];
#pragma unroll
    for (int r = 0; r < 4; ++r) l4[r] = __shfl(linv, (lane & 48) | (quad * 4 + r));
#pragma unroll
    for (int nt = 0; nt < 4; ++nt)
#pragma unroll
        for (int r = 0; r < 4; ++r)
            Pbf[16 * w + quad * 4 + r][qidx + 16 * nt] = f2bf(AO[nt][r] * l4[r]);
    __syncthreads();
    {
        unsigned short* dst = AObf + ((size_t)(b * S_ + s0 + jj)) * E_ + h * 64 + g * 16;
        *(uint4*)dst       = *(const uint4*)&Pbf[jj][g * 16];
        *(uint4*)(dst + 8) = *(const uint4*)&Pbf[jj][g * 16 + 8];
    }
}

// ---------------- output GEMM (bf16 MFMA): out = AObf @ W2^T + bo ----------------
__global__ __launch_bounds__(256) void out_gemm_bf(const unsigned short* __restrict__ A,
                                                   const unsigned short* __restrict__ W2,
                                                   const float* __restrict__ bo,
                                                   float* __restrict__ out) {
    __shared__ unsigned short At[64][72];
    __shared__ unsigned short Bt[64][72];
    const int tid = threadIdx.x;
    const int w = tid >> 6, lane = tid & 63;
    const int quad = lane >> 4, qidx = lane & 15;
    const int et = blockIdx.x & 7, rt = blockIdx.x >> 3;
    const int r0 = rt * 64, e0 = et * 64;
    const int jj = tid >> 2, g = tid & 3;
    f32x4 acc[4] = {{0,0,0,0},{0,0,0,0},{0,0,0,0},{0,0,0,0}};

    for (int k0 = 0; k0 < 512; k0 += 64) {
        __syncthreads();
        {
            const unsigned short* sa = A + (size_t)(r0 + jj) * 512 + k0 + g * 16;
            *(uint4*)&At[jj][g * 16]     = *(const uint4*)sa;
            *(uint4*)&At[jj][g * 16 + 8] = *(const uint4*)(sa + 8);
            const unsigned short* sb = W2 + (size_t)(e0 + jj) * 512 + k0 + g * 16;
            *(uint4*)&Bt[jj][g * 16]     = *(const uint4*)sb;
            *(uint4*)&Bt[jj][g * 16 + 8] = *(const uint4*)(sb + 8);
        }
        __syncthreads();
#pragma unroll
        for (int ks = 0; ks < 2; ++ks) {
            bf16x8 aA = *(const bf16x8*)&At[16 * w + qidx][ks * 32 + quad * 8];
#pragma unroll
            for (int nt = 0; nt < 4; ++nt) {
                bf16x8 bW = *(const bf16x8*)&Bt[qidx + 16 * nt][ks * 32 + quad * 8];
                acc[nt] = __builtin_amdgcn_mfma_f32_16x16x32_bf16(aA, bW, acc[nt], 0, 0, 0);
            }
        }
    }
#pragma unroll
    for (int nt = 0; nt < 4; ++nt) {
        float bv = bo[e0 + qidx + 16 * nt];
#pragma unroll
        for (int r = 0; r < 4; ++r)
            out[(size_t)(r0 + 16 * w + quad * 4 + r) * 512 + e0 + qidx + 16 * nt] =
                acc[nt][r] + bv;
    }
}

extern "C" void kernel_launch(void* const* d_in, const int* in_sizes, int n_in,
                              void* d_out, int out_size, void* d_ws, size_t ws_size,
                              hipStream_t stream) {
    (void)in_sizes; (void)n_in; (void)out_size; (void)ws_size;
    const float* X  = (const float*)d_in[0];   // queries (K/V derive from it, per reference)
    const float* Wq = (const float*)d_in[3];
    const float* Wk = (const float*)d_in[4];
    const float* Wv = (const float*)d_in[5];
    const float* Wo = (const float*)d_in[6];
    const float* bo = (const float*)d_in[7];

    float* ws = (float*)d_ws;
    unsigned short* W2bf = (unsigned short*)ws;                       // 262144 us
    unsigned short* GT   = (unsigned short*)(ws + 131072);            // 4096 us
    unsigned short* Xbf  = (unsigned short*)(ws + 133120);            // 4,194,304 us
    unsigned short* XTg  = (unsigned short*)(ws + 133120 + 2097152);  // 4,194,304 us
    unsigned short* AObf = (unsigned short*)(ws + 133120 + 4194304);  // 4,194,304 us

    prep_GT  <<<16,   256, 0, stream>>>(Wq, Wk, GT);
    prep_W2bf<<<1024, 256, 0, stream>>>(Wo, Wv, W2bf);
    prep_X   <<<1024, 256, 0, stream>>>(X, Xbf, XTg);
    attn_mfma<<<1024, 256, 0, stream>>>(Xbf, XTg, GT, AObf);
    out_gemm_bf<<<1024, 256, 0, stream>>>(AObf, W2bf, bo, (float*)d_out);
}

// Round 3
// 187.993 us; speedup vs baseline: 3.6918x; 1.1435x over previous
//
#include <hip/hip_runtime.h>
#include <cstddef>

#define S_ 2048
#define E_ 512

typedef __attribute__((ext_vector_type(8)))  short bf16x8;
typedef __attribute__((ext_vector_type(16))) float f32x16;

__device__ __forceinline__ unsigned short f2bf(float f) {
    union { float f; unsigned u; } v; v.f = f;
    return (unsigned short)((v.u + 0x7FFFu + ((v.u >> 16) & 1u)) >> 16);
}
// pack two floats to bf16x2 (round-half-up): low16 = bf16(a), high16 = bf16(b)
__device__ __forceinline__ unsigned pk2bf(float a, float b) {
    union { float f; unsigned u; } x, y; x.f = a; y.f = b;
    return __builtin_amdgcn_perm(y.u + 0x8000u, x.u + 0x8000u, 0x07060302u);
}

// ---------------- fused weight prep ----------------
// blocks 0..15:   GT[c][d] = kScale * sum_e Wq[e][d]*Wk[e][c]   (kScale = log2(e)/8)
// blocks 16..1039: W2[e][h*64+c] = sum_d Wo[e][h*64+d]*Wv[d][c]
__global__ __launch_bounds__(256) void prep_w(const float* __restrict__ Wq,
                                              const float* __restrict__ Wk,
                                              const float* __restrict__ Wo,
                                              const float* __restrict__ Wv,
                                              unsigned short* __restrict__ GT,
                                              unsigned short* __restrict__ W2) {
    int bi = blockIdx.x;
    if (bi < 16) {
        int idx = bi * 256 + threadIdx.x;      // 4096
        int c = idx >> 6, d = idx & 63;
        float acc = 0.f;
#pragma unroll 8
        for (int e = 0; e < 64; ++e) acc += Wq[e * 64 + d] * Wk[e * 64 + c];
        GT[c * 64 + d] = f2bf(acc * 0.18033688011112042f);
    } else {
        int idx = (bi - 16) * 256 + threadIdx.x;   // 262144
        int e = idx >> 9, f = idx & 511;
        int h = f >> 6, c = f & 63;
        const float* wo = Wo + e * 512 + h * 64;
        float acc = 0.f;
#pragma unroll 8
        for (int d = 0; d < 64; ++d) acc += wo[d] * Wv[d * 64 + c];
        W2[idx] = f2bf(acc);
    }
}

// Xbf[b][s][e] = bf16(X);  XTg[b][h][d][s] = bf16(X[b][s][h*64+d])
__global__ __launch_bounds__(256) void prep_X(const float* __restrict__ X,
                                              unsigned short* __restrict__ Xbf,
                                              unsigned short* __restrict__ XTg) {
    __shared__ unsigned short T[64][72];
    const int tid = threadIdx.x;
    const int st = blockIdx.x & 31, h = (blockIdx.x >> 5) & 7, b = blockIdx.x >> 8;
    const int s0 = st * 64;
    const int j = tid >> 2, g = tid & 3;
    const float* src = X + ((size_t)(b * S_ + s0 + j) * E_) + h * 64 + g * 16;
    unsigned short us[16];
#pragma unroll
    for (int i = 0; i < 16; i += 4) {
        float4 f = *(const float4*)(src + i);
        us[i] = f2bf(f.x); us[i + 1] = f2bf(f.y);
        us[i + 2] = f2bf(f.z); us[i + 3] = f2bf(f.w);
    }
    size_t xb = ((size_t)(b * S_ + s0 + j) * E_) + h * 64 + g * 16;
    *(uint4*)&Xbf[xb]     = *(uint4*)&us[0];
    *(uint4*)&Xbf[xb + 8] = *(uint4*)&us[8];
#pragma unroll
    for (int i = 0; i < 16; ++i) T[g * 16 + i][j] = us[i];
    __syncthreads();
    const int d = tid >> 2;
    size_t tb = ((size_t)((b * 8 + h) * 64 + d)) * S_ + s0 + g * 16;
    *(uint4*)&XTg[tb]     = *(uint4*)&T[d][g * 16];
    *(uint4*)&XTg[tb + 8] = *(uint4*)&T[d][g * 16 + 8];
}

// ---------------- MFMA flash attention, Q-tile=128, 32x32x16, no-max softmax -------
// 512 blocks (b,h,qtile of 128), 4 waves; wave w owns queries [32w,32w+32).
// U (=X@G, scaled) and P are wave-private; X key-chunk staging is shared (2 barriers).
__global__ __launch_bounds__(256, 2) void attn_mfma(const unsigned short* __restrict__ Xbf,
                                                    const unsigned short* __restrict__ XTg,
                                                    const unsigned short* __restrict__ GT,
                                                    unsigned short* __restrict__ AObf) {
    __shared__ unsigned short Ubf[128][72];   // U[q][c], rows wave-private
    __shared__ unsigned short Xrm[64][72];    // X[j][d] key-chunk row-major (shared)
    __shared__ unsigned short XT [64][72];    // X^T[d][j] key-chunk (shared)
    __shared__ unsigned short Pbf[128][72];   // P[q][k], rows wave-private

    const int tid = threadIdx.x;
    const int w = tid >> 6, lane = tid & 63;
    const int lm = lane & 31, lh = lane >> 5;
    const int qt = blockIdx.x & 15, h = (blockIdx.x >> 4) & 7, b = blockIdx.x >> 7;
    const int s0 = qt * 128;

    // ---- stage the 128 Q-rows into Xrm(0..63)+XT(0..63 as rows 64..127) temporarily
    {
        const int r = tid >> 1, c = (tid & 1) * 32;
        const unsigned short* src = Xbf + ((size_t)(b * S_ + s0 + r)) * E_ + h * 64 + c;
        unsigned short* dst = (r < 64) ? &Xrm[r][c] : &XT[r - 64][c];
#pragma unroll
        for (int u = 0; u < 4; ++u) *(uint4*)(dst + u * 8) = *(const uint4*)(src + u * 8);
    }
    __syncthreads();

    // ---- U = Xq @ (G*kScale): D[m=q][n=c]; write into wave-private Ubf rows
    {
        f32x16 uacc[2];
#pragma unroll
        for (int nt = 0; nt < 2; ++nt)
#pragma unroll
            for (int i = 0; i < 16; ++i) uacc[nt][i] = 0.f;
        const int q = 32 * w + lm;
        const unsigned short* arow = (q < 64) ? &Xrm[q][0] : &XT[q - 64][0];
#pragma unroll
        for (int ks = 0; ks < 4; ++ks) {
            bf16x8 aX = *(const bf16x8*)(arow + ks * 16 + lh * 8);
#pragma unroll
            for (int nt = 0; nt < 2; ++nt) {
                bf16x8 bG = *(const bf16x8*)&GT[(lm + 32 * nt) * 64 + ks * 16 + lh * 8];
                uacc[nt] = __builtin_amdgcn_mfma_f32_32x32x16_bf16(aX, bG, uacc[nt], 0, 0, 0);
            }
        }
#pragma unroll
        for (int nt = 0; nt < 2; ++nt)
#pragma unroll
            for (int r = 0; r < 16; ++r) {
                int qrow = (r & 3) + 8 * (r >> 2) + 4 * lh;
                Ubf[32 * w + qrow][lm + 32 * nt] = f2bf(uacc[nt][r]);
            }
    }

    float lsum = 0.f;
    f32x16 AO[2];
#pragma unroll
    for (int nt = 0; nt < 2; ++nt)
#pragma unroll
        for (int i = 0; i < 16; ++i) AO[nt][i] = 0.f;

    for (int sk = 0; sk < S_; sk += 64) {
        __syncthreads();   // prev chunk readers done (first iter: U-proj temp reads done)
        {
            const int r = tid >> 2, c = (tid & 3) * 16;
            const unsigned short* src = Xbf + ((size_t)(b * S_ + sk + r)) * E_ + h * 64 + c;
            *(uint4*)&Xrm[r][c]     = *(const uint4*)src;
            *(uint4*)&Xrm[r][c + 8] = *(const uint4*)(src + 8);
            const unsigned short* srct = XTg + ((size_t)((b * 8 + h) * 64 + r)) * S_ + sk + c;
            *(uint4*)&XT[r][c]      = *(const uint4*)srct;
            *(uint4*)&XT[r][c + 8]  = *(const uint4*)(srct + 8);
        }
        __syncthreads();

        // Sc^T[k][q] = sum_d X[k][d] U[q][d]; A = Xrm rows (m=key), B = Ubf rows (n=q)
        f32x16 sc[2];
#pragma unroll
        for (int mt = 0; mt < 2; ++mt)
#pragma unroll
            for (int i = 0; i < 16; ++i) sc[mt][i] = 0.f;
#pragma unroll
        for (int ks = 0; ks < 4; ++ks) {
            bf16x8 bU = *(const bf16x8*)&Ubf[32 * w + lm][ks * 16 + lh * 8];
#pragma unroll
            for (int mt = 0; mt < 2; ++mt) {
                bf16x8 aX = *(const bf16x8*)&Xrm[32 * mt + lm][ks * 16 + lh * 8];
                sc[mt] = __builtin_amdgcn_mfma_f32_32x32x16_bf16(aX, bU, sc[mt], 0, 0, 0);
            }
        }

        // no-max softmax numerators; P[q][k] rows wave-private, 8B packed writes
#pragma unroll
        for (int mt = 0; mt < 2; ++mt)
#pragma unroll
            for (int rg = 0; rg < 4; ++rg) {
                float p0 = exp2f(sc[mt][rg * 4 + 0]);
                float p1 = exp2f(sc[mt][rg * 4 + 1]);
                float p2 = exp2f(sc[mt][rg * 4 + 2]);
                float p3 = exp2f(sc[mt][rg * 4 + 3]);
                lsum += (p0 + p1) + (p2 + p3);
                unsigned u01 = pk2bf(p0, p1), u23 = pk2bf(p2, p3);
                int kc = 32 * mt + 8 * rg + 4 * lh;
                *(uint2*)&Pbf[32 * w + lm][kc] = make_uint2(u01, u23);
            }

        // PV: AO[q][d] += P[q][j] X[j][d]; A = Pbf rows (m=q), B = XT rows (n=d)
#pragma unroll
        for (int js = 0; js < 4; ++js) {
            bf16x8 aP = *(const bf16x8*)&Pbf[32 * w + lm][js * 16 + lh * 8];
#pragma unroll
            for (int nt = 0; nt < 2; ++nt) {
                bf16x8 bX = *(const bf16x8*)&XT[lm + 32 * nt][js * 16 + lh * 8];
                AO[nt] = __builtin_amdgcn_mfma_f32_32x32x16_bf16(aP, bX, AO[nt], 0, 0, 0);
            }
        }
    }

    // ---- epilogue: l-combine, normalize, coalesced store via Pbf reuse
    lsum += __shfl_xor(lsum, 32);
    float linv = 1.0f / lsum;                 // valid for q = lm in both lane halves
    float lrow[16];
#pragma unroll
    for (int r = 0; r < 16; ++r)
        lrow[r] = __shfl(linv, (r & 3) + 8 * (r >> 2) + 4 * lh);
#pragma unroll
    for (int nt = 0; nt < 2; ++nt)
#pragma unroll
        for (int r = 0; r < 16; ++r) {
            int qrow = (r & 3) + 8 * (r >> 2) + 4 * lh;
            Pbf[32 * w + qrow][lm + 32 * nt] = f2bf(AO[nt][r] * lrow[r]);
        }
    __syncthreads();
    {
        const int r = tid >> 1, c = (tid & 1) * 32;
        unsigned short* dst = AObf + ((size_t)(b * S_ + s0 + r)) * E_ + h * 64 + c;
#pragma unroll
        for (int u = 0; u < 4; ++u)
            *(uint4*)(dst + u * 8) = *(const uint4*)&Pbf[r][c + u * 8];
    }
}

// ---------------- output GEMM (bf16 MFMA): out = AObf @ W2^T + bo ----------------
__global__ __launch_bounds__(256) void out_gemm_bf(const unsigned short* __restrict__ A,
                                                   const unsigned short* __restrict__ W2,
                                                   const float* __restrict__ bo,
                                                   float* __restrict__ out) {
    __shared__ unsigned short At[64][72];
    __shared__ unsigned short Bt[64][72];
    typedef __attribute__((ext_vector_type(4))) float f32x4;
    const int tid = threadIdx.x;
    const int w = tid >> 6, lane = tid & 63;
    const int quad = lane >> 4, qidx = lane & 15;
    const int et = blockIdx.x & 7, rt = blockIdx.x >> 3;
    const int r0 = rt * 64, e0 = et * 64;
    const int jj = tid >> 2, g = tid & 3;
    f32x4 acc[4] = {{0,0,0,0},{0,0,0,0},{0,0,0,0},{0,0,0,0}};

    for (int k0 = 0; k0 < 512; k0 += 64) {
        __syncthreads();
        {
            const unsigned short* sa = A + (size_t)(r0 + jj) * 512 + k0 + g * 16;
            *(uint4*)&At[jj][g * 16]     = *(const uint4*)sa;
            *(uint4*)&At[jj][g * 16 + 8] = *(const uint4*)(sa + 8);
            const unsigned short* sb = W2 + (size_t)(e0 + jj) * 512 + k0 + g * 16;
            *(uint4*)&Bt[jj][g * 16]     = *(const uint4*)sb;
            *(uint4*)&Bt[jj][g * 16 + 8] = *(const uint4*)(sb + 8);
        }
        __syncthreads();
#pragma unroll
        for (int ks = 0; ks < 2; ++ks) {
            bf16x8 aA = *(const bf16x8*)&At[16 * w + qidx][ks * 32 + quad * 8];
#pragma unroll
            for (int nt = 0; nt < 4; ++nt) {
                bf16x8 bW = *(const bf16x8*)&Bt[qidx + 16 * nt][ks * 32 + quad * 8];
                acc[nt] = __builtin_amdgcn_mfma_f32_16x16x32_bf16(aA, bW, acc[nt], 0, 0, 0);
            }
        }
    }
#pragma unroll
    for (int nt = 0; nt < 4; ++nt) {
        float bv = bo[e0 + qidx + 16 * nt];
#pragma unroll
        for (int r = 0; r < 4; ++r)
            out[(size_t)(r0 + 16 * w + quad * 4 + r) * 512 + e0 + qidx + 16 * nt] =
                acc[nt][r] + bv;
    }
}

extern "C" void kernel_launch(void* const* d_in, const int* in_sizes, int n_in,
                              void* d_out, int out_size, void* d_ws, size_t ws_size,
                              hipStream_t stream) {
    (void)in_sizes; (void)n_in; (void)out_size; (void)ws_size;
    const float* X  = (const float*)d_in[0];   // queries (K/V derive from it, per reference)
    const float* Wq = (const float*)d_in[3];
    const float* Wk = (const float*)d_in[4];
    const float* Wv = (const float*)d_in[5];
    const float* Wo = (const float*)d_in[6];
    const float* bo = (const float*)d_in[7];

    float* ws = (float*)d_ws;
    unsigned short* W2bf = (unsigned short*)ws;                       // 262144 us
    unsigned short* GT   = (unsigned short*)(ws + 131072);            // 4096 us
    unsigned short* Xbf  = (unsigned short*)(ws + 133120);            // 4,194,304 us
    unsigned short* XTg  = (unsigned short*)(ws + 133120 + 2097152);  // 4,194,304 us
    unsigned short* AObf = (unsigned short*)(ws + 133120 + 4194304);  // 4,194,304 us

    prep_w   <<<1040, 256, 0, stream>>>(Wq, Wk, Wo, Wv, GT, W2bf);
    prep_X   <<<1024, 256, 0, stream>>>(X, Xbf, XTg);
    attn_mfma<<<512,  256, 0, stream>>>(Xbf, XTg, GT, AObf);
    out_gemm_bf<<<1024, 256, 0, stream>>>(AObf, W2bf, bo, (float*)d_out);
}

// Round 4
// 181.051 us; speedup vs baseline: 3.8334x; 1.0383x over previous
//
#include <hip/hip_runtime.h>
#include <cstddef>

#define S_ 2048
#define E_ 512

typedef __attribute__((ext_vector_type(8)))  short bf16x8;
typedef __attribute__((ext_vector_type(16))) float f32x16;

__device__ __forceinline__ unsigned short f2bf(float f) {
    union { float f; unsigned u; } v; v.f = f;
    return (unsigned short)((v.u + 0x7FFFu + ((v.u >> 16) & 1u)) >> 16);
}
// pack two floats to bf16x2 (round-half-up): low16 = bf16(a), high16 = bf16(b)
__device__ __forceinline__ unsigned pk2bf(float a, float b) {
    union { float f; unsigned u; } x, y; x.f = a; y.f = b;
    return __builtin_amdgcn_perm(y.u + 0x8000u, x.u + 0x8000u, 0x07060302u);
}

// ---------------- fused weight prep ----------------
// blocks 0..15:    GT[c][d] = kScale * sum_e Wq[e][d]*Wk[e][c]  (kScale = log2(e)/8)
// blocks 16..1039: W2[e][h*64+c] = sum_d Wo[e][h*64+d]*Wv[d][c]
__global__ __launch_bounds__(256) void prep_w(const float* __restrict__ Wq,
                                              const float* __restrict__ Wk,
                                              const float* __restrict__ Wo,
                                              const float* __restrict__ Wv,
                                              unsigned short* __restrict__ GT,
                                              unsigned short* __restrict__ W2) {
    int bi = blockIdx.x;
    if (bi < 16) {
        int idx = bi * 256 + threadIdx.x;
        int c = idx >> 6, d = idx & 63;
        float acc = 0.f;
#pragma unroll 8
        for (int e = 0; e < 64; ++e) acc += Wq[e * 64 + d] * Wk[e * 64 + c];
        GT[c * 64 + d] = f2bf(acc * 0.18033688011112042f);
    } else {
        int idx = (bi - 16) * 256 + threadIdx.x;
        int e = idx >> 9, f = idx & 511;
        int h = f >> 6, c = f & 63;
        const float* wo = Wo + e * 512 + h * 64;
        float acc = 0.f;
#pragma unroll 8
        for (int d = 0; d < 64; ++d) acc += wo[d] * Wv[d * 64 + c];
        W2[idx] = f2bf(acc);
    }
}

// Xbf[b][s][e] = bf16(X)
// XTg[b][h][d][sblk*16 + t] = bf16(X[b][sblk*16 + perm16[t]][h*64+d])
// perm16 swaps the middle quads of each 16-block so PV A-frags are contiguous
// while PV B-frags fall out of the QK C-layout registers untouched.
__global__ __launch_bounds__(256) void prep_X(const float* __restrict__ X,
                                              unsigned short* __restrict__ Xbf,
                                              unsigned short* __restrict__ XTg) {
    __shared__ unsigned short T[64][72];
    const int tid = threadIdx.x;
    const int st = blockIdx.x & 31, h = (blockIdx.x >> 5) & 7, b = blockIdx.x >> 8;
    const int s0 = st * 64;
    const int j = tid >> 2, g = tid & 3;
    const float* src = X + ((size_t)(b * S_ + s0 + j) * E_) + h * 64 + g * 16;
    unsigned short us[16];
#pragma unroll
    for (int i = 0; i < 16; i += 4) {
        float4 f = *(const float4*)(src + i);
        us[i] = f2bf(f.x); us[i + 1] = f2bf(f.y);
        us[i + 2] = f2bf(f.z); us[i + 3] = f2bf(f.w);
    }
    size_t xb = ((size_t)(b * S_ + s0 + j) * E_) + h * 64 + g * 16;
    *(uint4*)&Xbf[xb]     = *(uint4*)&us[0];
    *(uint4*)&Xbf[xb + 8] = *(uint4*)&us[8];
#pragma unroll
    for (int i = 0; i < 16; ++i) T[g * 16 + i][j] = us[i];
    __syncthreads();
    const int d = tid >> 2;
    const int pm[16] = {0,1,2,3,8,9,10,11,4,5,6,7,12,13,14,15};
    unsigned short o[16];
#pragma unroll
    for (int i = 0; i < 16; ++i) o[i] = T[d][g * 16 + pm[i]];
    size_t tb = ((size_t)((b * 8 + h) * 64 + d)) * S_ + s0 + g * 16;
    *(uint4*)&XTg[tb]     = *(uint4*)&o[0];
    *(uint4*)&XTg[tb + 8] = *(uint4*)&o[8];
}

// ---------------- MFMA flash attention ----------------
// 512 blocks (b,h,qtile of 128), 4 waves; wave w owns queries [32w,32w+32).
// U in regs (B-frags), P in regs (permuted-j PV B-frags), AO^T accumulator.
// LDS: one 18.4 KB union -> 4 blocks/CU.
__global__ __launch_bounds__(256, 4) void attn_mfma(const unsigned short* __restrict__ Xbf,
                                                    const unsigned short* __restrict__ XTg,
                                                    const unsigned short* __restrict__ GT,
                                                    unsigned short* __restrict__ AObf) {
    __shared__ union SM {
        unsigned short Q[128][72];                                   // startup: Q rows / U rows
        struct { unsigned short Xrm[64][72], XT[64][72]; } c;        // chunk staging
        unsigned short AOt[128][72];                                 // epilogue bounce [q][d]
    } sm;

    const int tid = threadIdx.x;
    const int w = tid >> 6, lane = tid & 63;
    const int lm = lane & 31, lh = lane >> 5;
    const int qt = blockIdx.x & 15, h = (blockIdx.x >> 4) & 7, b = blockIdx.x >> 7;
    const int s0 = qt * 128;

    // stage 128 Q rows
    {
        const int r = tid >> 1, c = (tid & 1) * 32;
        const unsigned short* src = Xbf + ((size_t)(b * S_ + s0 + r)) * E_ + h * 64 + c;
#pragma unroll
        for (int u = 0; u < 4; ++u) *(uint4*)&sm.Q[r][c + u * 8] = *(const uint4*)(src + u * 8);
    }
    __syncthreads();

    // U = Xq @ (G*kScale); round-trip through own wave's rows, keep B-frags in regs
    bf16x8 Ufrag[4];
    {
        f32x16 ua[2];
#pragma unroll
        for (int nt = 0; nt < 2; ++nt)
#pragma unroll
            for (int i = 0; i < 16; ++i) ua[nt][i] = 0.f;
#pragma unroll
        for (int ks = 0; ks < 4; ++ks) {
            bf16x8 aQ = *(const bf16x8*)&sm.Q[32 * w + lm][ks * 16 + lh * 8];
#pragma unroll
            for (int nt = 0; nt < 2; ++nt) {
                bf16x8 bG = *(const bf16x8*)&GT[(lm + 32 * nt) * 64 + ks * 16 + lh * 8];
                ua[nt] = __builtin_amdgcn_mfma_f32_32x32x16_bf16(aQ, bG, ua[nt], 0, 0, 0);
            }
        }
#pragma unroll
        for (int nt = 0; nt < 2; ++nt)
#pragma unroll
            for (int r = 0; r < 16; ++r)
                sm.Q[32 * w + (r & 3) + 8 * (r >> 2) + 4 * lh][lm + 32 * nt] = f2bf(ua[nt][r]);
#pragma unroll
        for (int ks = 0; ks < 4; ++ks)
            Ufrag[ks] = *(const bf16x8*)&sm.Q[32 * w + lm][ks * 16 + lh * 8];
    }

    float lsum = 0.f;
    f32x16 AO[2];
#pragma unroll
    for (int mt = 0; mt < 2; ++mt)
#pragma unroll
        for (int i = 0; i < 16; ++i) AO[mt][i] = 0.f;

    const unsigned short* srcX = Xbf + ((size_t)(b * S_ + (tid >> 2))) * E_ + h * 64 + (tid & 3) * 16;
    const unsigned short* srcT = XTg + ((size_t)((b * 8 + h) * 64 + (tid >> 2))) * S_ + (tid & 3) * 16;

    for (int sk = 0; sk < S_; sk += 64) {
        __syncthreads();   // prior readers done before staging overwrites the union
        {
            const unsigned short* sx = srcX + (size_t)sk * E_;
            const int r = tid >> 2, c = (tid & 3) * 16;
            *(uint4*)&sm.c.Xrm[r][c]     = *(const uint4*)sx;
            *(uint4*)&sm.c.Xrm[r][c + 8] = *(const uint4*)(sx + 8);
            const unsigned short* st = srcT + sk;
            *(uint4*)&sm.c.XT[r][c]      = *(const uint4*)st;
            *(uint4*)&sm.c.XT[r][c + 8]  = *(const uint4*)(st + 8);
        }
        __syncthreads();

        // QK: Sc^T[k][q], A = Xrm rows, B = Ufrag (regs)
        f32x16 sc[2];
#pragma unroll
        for (int mt = 0; mt < 2; ++mt)
#pragma unroll
            for (int i = 0; i < 16; ++i) sc[mt][i] = 0.f;
#pragma unroll
        for (int ks = 0; ks < 4; ++ks)
#pragma unroll
            for (int mt = 0; mt < 2; ++mt) {
                bf16x8 aX = *(const bf16x8*)&sm.c.Xrm[32 * mt + lm][ks * 16 + lh * 8];
                sc[mt] = __builtin_amdgcn_mfma_f32_32x32x16_bf16(aX, Ufrag[ks], sc[mt], 0, 0, 0);
            }

        // softmax numerators (no-max), packed in PV B-frag order
        unsigned up[16];
#pragma unroll
        for (int mt = 0; mt < 2; ++mt)
#pragma unroll
            for (int qq = 0; qq < 4; ++qq) {
                float p0 = exp2f(sc[mt][qq * 4 + 0]);
                float p1 = exp2f(sc[mt][qq * 4 + 1]);
                float p2 = exp2f(sc[mt][qq * 4 + 2]);
                float p3 = exp2f(sc[mt][qq * 4 + 3]);
                lsum += (p0 + p1) + (p2 + p3);
                up[mt * 8 + 2 * qq]     = pk2bf(p0, p1);
                up[mt * 8 + 2 * qq + 1] = pk2bf(p2, p3);
            }

        // PV: AO^T[d][q] += X^T[d][j] P[q][j]; A = permuted XT rows, B = up regs
#pragma unroll
        for (int js = 0; js < 4; ++js) {
            union { unsigned u[4]; bf16x8 v; } bP;
            bP.u[0] = up[js * 4 + 0]; bP.u[1] = up[js * 4 + 1];
            bP.u[2] = up[js * 4 + 2]; bP.u[3] = up[js * 4 + 3];
#pragma unroll
            for (int mt = 0; mt < 2; ++mt) {
                bf16x8 aT = *(const bf16x8*)&sm.c.XT[32 * mt + lm][js * 16 + lh * 8];
                AO[mt] = __builtin_amdgcn_mfma_f32_32x32x16_bf16(aT, bP.v, AO[mt], 0, 0, 0);
            }
        }
    }

    // epilogue: l is column-aligned with AO^T (q = lm) — no broadcast needed
    lsum += __shfl_xor(lsum, 32);
    float linv = 1.0f / lsum;
    __syncthreads();   // last chunk's reads done before bounce overwrite
#pragma unroll
    for (int mt = 0; mt < 2; ++mt)
#pragma unroll
        for (int qq = 0; qq < 4; ++qq) {
            int d0 = 32 * mt + 8 * qq + 4 * lh;
            *(unsigned*)&sm.AOt[32 * w + lm][d0] =
                pk2bf(AO[mt][qq * 4 + 0] * linv, AO[mt][qq * 4 + 1] * linv);
            *(unsigned*)&sm.AOt[32 * w + lm][d0 + 2] =
                pk2bf(AO[mt][qq * 4 + 2] * linv, AO[mt][qq * 4 + 3] * linv);
        }
    __syncthreads();
    {
        const int r = tid >> 1, c = (tid & 1) * 32;
        unsigned short* dst = AObf + ((size_t)(b * S_ + s0 + r)) * E_ + h * 64 + c;
#pragma unroll
        for (int u = 0; u < 4; ++u)
            *(uint4*)(dst + u * 8) = *(const uint4*)&sm.AOt[r][c + u * 8];
    }
}

// ---------------- output GEMM: out = AObf @ W2^T + bo (64x128 tiles) ----------------
__global__ __launch_bounds__(256) void out_gemm_bf(const unsigned short* __restrict__ A,
                                                   const unsigned short* __restrict__ W2,
                                                   const float* __restrict__ bo,
                                                   float* __restrict__ out) {
    __shared__ unsigned short At[64][72];
    __shared__ unsigned short Bt[128][72];
    const int tid = threadIdx.x;
    const int w = tid >> 6, lane = tid & 63;
    const int lm = lane & 31, lh = lane >> 5;
    const int et = blockIdx.x & 3, rt = blockIdx.x >> 2;   // 4 col-tiles x 128 row-tiles
    const int r0 = rt * 64, e0 = et * 128;
    f32x16 acc[2];
#pragma unroll
    for (int mt = 0; mt < 2; ++mt)
#pragma unroll
        for (int i = 0; i < 16; ++i) acc[mt][i] = 0.f;

    for (int k0 = 0; k0 < 512; k0 += 64) {
        __syncthreads();
        {
            const int r = tid >> 2, c = (tid & 3) * 16;
            const unsigned short* sa = A + (size_t)(r0 + r) * 512 + k0 + c;
            *(uint4*)&At[r][c]     = *(const uint4*)sa;
            *(uint4*)&At[r][c + 8] = *(const uint4*)(sa + 8);
            const int r2 = tid >> 1, c2 = (tid & 1) * 32;
            const unsigned short* sb = W2 + (size_t)(e0 + r2) * 512 + k0 + c2;
#pragma unroll
            for (int u = 0; u < 4; ++u)
                *(uint4*)&Bt[r2][c2 + u * 8] = *(const uint4*)(sb + u * 8);
        }
        __syncthreads();
#pragma unroll
        for (int ks = 0; ks < 4; ++ks) {
            bf16x8 bW = *(const bf16x8*)&Bt[32 * w + lm][ks * 16 + lh * 8];
#pragma unroll
            for (int mt = 0; mt < 2; ++mt) {
                bf16x8 aA = *(const bf16x8*)&At[32 * mt + lm][ks * 16 + lh * 8];
                acc[mt] = __builtin_amdgcn_mfma_f32_32x32x16_bf16(aA, bW, acc[mt], 0, 0, 0);
            }
        }
    }
    float bv = bo[e0 + 32 * w + lm];
#pragma unroll
    for (int mt = 0; mt < 2; ++mt)
#pragma unroll
        for (int r = 0; r < 16; ++r) {
            int srow = r0 + 32 * mt + (r & 3) + 8 * (r >> 2) + 4 * lh;
            out[(size_t)srow * 512 + e0 + 32 * w + lm] = acc[mt][r] + bv;
        }
}

extern "C" void kernel_launch(void* const* d_in, const int* in_sizes, int n_in,
                              void* d_out, int out_size, void* d_ws, size_t ws_size,
                              hipStream_t stream) {
    (void)in_sizes; (void)n_in; (void)out_size; (void)ws_size;
    const float* X  = (const float*)d_in[0];   // queries (K/V derive from it, per reference)
    const float* Wq = (const float*)d_in[3];
    const float* Wk = (const float*)d_in[4];
    const float* Wv = (const float*)d_in[5];
    const float* Wo = (const float*)d_in[6];
    const float* bo = (const float*)d_in[7];

    float* ws = (float*)d_ws;
    unsigned short* W2bf = (unsigned short*)ws;                       // 262144 us
    unsigned short* GT   = (unsigned short*)(ws + 131072);            // 4096 us
    unsigned short* Xbf  = (unsigned short*)(ws + 133120);            // 4,194,304 us
    unsigned short* XTg  = (unsigned short*)(ws + 133120 + 2097152);  // 4,194,304 us
    unsigned short* AObf = (unsigned short*)(ws + 133120 + 4194304);  // 4,194,304 us

    prep_w     <<<1040, 256, 0, stream>>>(Wq, Wk, Wo, Wv, GT, W2bf);
    prep_X     <<<1024, 256, 0, stream>>>(X, Xbf, XTg);
    attn_mfma  <<<512,  256, 0, stream>>>(Xbf, XTg, GT, AObf);
    out_gemm_bf<<<512,  256, 0, stream>>>(AObf, W2bf, bo, (float*)d_out);
}